// Round 1
// baseline (295.190 us; speedup 1.0000x reference)
//
#include <hip/hip_runtime.h>

// Problem constants (fixed by setup_inputs in the reference)
#define BB 64      // batch
#define II 1024    // input dim
#define HH 4096    // hidden dim
#define OO 256     // output dim
#define EPSI 0.1f

// ---------------------------------------------------------------------------
// Kernel 1: per-row reductions.
//   blocks [0, HH):        nscaled[j] = -EPS * sum_i |W1[j,i]|
//   blocks [HH, HH+OO):    nnrow[o]   = 4096 * sum_j W2[o,j] + bias2[o]
// 256 threads/block; W1 row = 1024 floats = 256 * float4 (one per thread);
// W2 row = 4096 floats = 4 float4 per thread.
// ---------------------------------------------------------------------------
__global__ __launch_bounds__(256) void prep_kernel(
    const float* __restrict__ W1, const float* __restrict__ W2,
    const float* __restrict__ bias2,
    float* __restrict__ nscaled, float* __restrict__ nnrow) {
  const int bid = blockIdx.x;
  const int tid = threadIdx.x;
  __shared__ float red[4];

  float s = 0.0f;
  if (bid < HH) {
    const float4* row = (const float4*)(W1 + (size_t)bid * II);
    float4 v = row[tid];
    s = fabsf(v.x) + fabsf(v.y) + fabsf(v.z) + fabsf(v.w);
  } else {
    const int o = bid - HH;
    const float4* row = (const float4*)(W2 + (size_t)o * HH);
#pragma unroll
    for (int k = 0; k < 4; ++k) {
      float4 v = row[tid + 256 * k];
      s += v.x + v.y + v.z + v.w;
    }
  }

  // wave64 shuffle reduce, then 4-wave LDS reduce
#pragma unroll
  for (int off = 32; off > 0; off >>= 1) s += __shfl_down(s, off);
  if ((tid & 63) == 0) red[tid >> 6] = s;
  __syncthreads();
  if (tid == 0) {
    float t = red[0] + red[1] + red[2] + red[3];
    if (bid < HH) {
      nscaled[bid] = -EPSI * t;
    } else {
      const int o = bid - HH;
      nnrow[o] = 4096.0f * t + bias2[o];
    }
  }
}

// ---------------------------------------------------------------------------
// Kernel 2: the big write. One block per (b,o) row of pert (16384 blocks).
//   pert[b,o,j] = y[b,o] ? sign(W2[o,j]) * nscaled[j] : 0
// 256 threads x 4 float4 stores = 4096 floats/row, fully coalesced (1 KB per
// wave store instruction). Thread 0 also writes nn_output[b,o] = nnrow[o].
// ---------------------------------------------------------------------------
__global__ __launch_bounds__(256) void write_kernel(
    const int* __restrict__ y, const float* __restrict__ W2,
    const float* __restrict__ nscaled, const float* __restrict__ nnrow,
    float* __restrict__ out) {
  const int r = blockIdx.x;        // r = b*OO + o
  const int o = r & (OO - 1);
  const int tid = threadIdx.x;

  if (tid == 0) out[r] = nnrow[o];  // nn_output broadcast over b

  float4* dst = (float4*)(out + (size_t)BB * OO + (size_t)r * HH);
  const int yv = y[r];              // block-uniform -> scalar load

  if (yv == 0) {
    const float4 z = {0.f, 0.f, 0.f, 0.f};
#pragma unroll
    for (int k = 0; k < 4; ++k) dst[tid + 256 * k] = z;
  } else {
    const float4* w  = (const float4*)(W2 + (size_t)o * HH);
    const float4* ns = (const float4*)nscaled;
#pragma unroll
    for (int k = 0; k < 4; ++k) {
      float4 wv = w[tid + 256 * k];
      float4 nv = ns[tid + 256 * k];
      float4 p;
      p.x = nv.x * ((wv.x > 0.f) ? 1.f : ((wv.x < 0.f) ? -1.f : 0.f));
      p.y = nv.y * ((wv.y > 0.f) ? 1.f : ((wv.y < 0.f) ? -1.f : 0.f));
      p.z = nv.z * ((wv.z > 0.f) ? 1.f : ((wv.z < 0.f) ? -1.f : 0.f));
      p.w = nv.w * ((wv.w > 0.f) ? 1.f : ((wv.w < 0.f) ? -1.f : 0.f));
      dst[tid + 256 * k] = p;
    }
  }
}

extern "C" void kernel_launch(void* const* d_in, const int* in_sizes, int n_in,
                              void* d_out, int out_size, void* d_ws, size_t ws_size,
                              hipStream_t stream) {
  // setup_inputs order: x, y, W1, W2, bias1, bias2
  const int*   y     = (const int*)d_in[1];
  const float* W1    = (const float*)d_in[2];
  const float* W2    = (const float*)d_in[3];
  const float* bias2 = (const float*)d_in[5];
  float* out = (float*)d_out;

  // workspace: nscaled[HH] then nnrow[OO]  (17.4 KB)
  float* nscaled = (float*)d_ws;
  float* nnrow   = nscaled + HH;

  prep_kernel<<<HH + OO, 256, 0, stream>>>(W1, W2, bias2, nscaled, nnrow);
  write_kernel<<<BB * OO, 256, 0, stream>>>(y, W2, nscaled, nnrow, out);
}

// Round 3
// 288.665 us; speedup vs baseline: 1.0226x; 1.0226x over previous
//
#include <hip/hip_runtime.h>

// Problem constants (fixed by setup_inputs in the reference)
#define BB 64      // batch
#define II 1024    // input dim
#define HH 4096    // hidden dim
#define OO 256     // output dim
#define EPSI 0.1f
#define BCHUNK 8   // batches per write-block

// native clang vector type — required by __builtin_nontemporal_store
typedef float vf4 __attribute__((ext_vector_type(4)));

// ---------------------------------------------------------------------------
// Kernel 1: per-row reductions.
//   blocks [0, HH):      nscaled[j] = -EPS * sum_i |W1[j,i]|        -> ws
//   blocks [HH, HH+OO):  nn = 4096*sum_j W2[o,j] + bias2[o]
//                        -> written directly to out[b*OO+o] for all b
// ---------------------------------------------------------------------------
__global__ __launch_bounds__(256) void prep_kernel(
    const float* __restrict__ W1, const float* __restrict__ W2,
    const float* __restrict__ bias2,
    float* __restrict__ nscaled, float* __restrict__ out) {
  const int bid = blockIdx.x;
  const int tid = threadIdx.x;
  __shared__ float red[4];
  __shared__ float bval;

  float s = 0.0f;
  if (bid < HH) {
    const float4* row = (const float4*)(W1 + (size_t)bid * II);
    float4 v = row[tid];
    s = fabsf(v.x) + fabsf(v.y) + fabsf(v.z) + fabsf(v.w);
  } else {
    const int o = bid - HH;
    const float4* row = (const float4*)(W2 + (size_t)o * HH);
#pragma unroll
    for (int k = 0; k < 4; ++k) {
      float4 v = row[tid + 256 * k];
      s += v.x + v.y + v.z + v.w;
    }
  }

  // wave64 shuffle reduce, then 4-wave LDS reduce
#pragma unroll
  for (int off = 32; off > 0; off >>= 1) s += __shfl_down(s, off);
  if ((tid & 63) == 0) red[tid >> 6] = s;
  __syncthreads();
  if (tid == 0) {
    float t = red[0] + red[1] + red[2] + red[3];
    if (bid < HH) {
      nscaled[bid] = -EPSI * t;
    } else {
      bval = 4096.0f * t + bias2[bid - HH];
    }
  }
  if (bid >= HH) {
    __syncthreads();
    // broadcast nn_output over the batch: out[b*OO + o], b = tid (64 stores)
    if (tid < BB) out[(size_t)tid * OO + (bid - HH)] = bval;
  }
}

// ---------------------------------------------------------------------------
// Kernel 2: the big write. Grid = OO * (BB/BCHUNK) = 2048 blocks.
// Block (o, bc): load W2[o,:] + nscaled once, precompute
//   sv[j] = sign(W2[o,j]) * (-EPS*||W1[j]||_1)   (16 floats/thread, registers)
// then stream BCHUNK rows of non-temporal float4 stores:
//   pert[b,o,j] = y[b,o] * sv[j]    (y in {0,1})
// ---------------------------------------------------------------------------
__global__ __launch_bounds__(256) void write_kernel(
    const int* __restrict__ y, const float* __restrict__ W2,
    const float* __restrict__ nscaled, float* __restrict__ out) {
  const int o  = blockIdx.x & (OO - 1);
  const int bc = blockIdx.x >> 8;   // batch chunk
  const int tid = threadIdx.x;

  const float4* w  = (const float4*)(W2 + (size_t)o * HH);
  const float4* ns = (const float4*)nscaled;

  vf4 sv[4];
#pragma unroll
  for (int k = 0; k < 4; ++k) {
    float4 wv = w[tid + 256 * k];
    float4 nv = ns[tid + 256 * k];
    sv[k].x = nv.x * ((wv.x > 0.f) ? 1.f : ((wv.x < 0.f) ? -1.f : 0.f));
    sv[k].y = nv.y * ((wv.y > 0.f) ? 1.f : ((wv.y < 0.f) ? -1.f : 0.f));
    sv[k].z = nv.z * ((wv.z > 0.f) ? 1.f : ((wv.z < 0.f) ? -1.f : 0.f));
    sv[k].w = nv.w * ((wv.w > 0.f) ? 1.f : ((wv.w < 0.f) ? -1.f : 0.f));
  }

  float* pert = out + (size_t)BB * OO;
#pragma unroll
  for (int i = 0; i < BCHUNK; ++i) {
    const int b = bc * BCHUNK + i;
    const int r = b * OO + o;
    const float yf = (float)y[r];   // block-uniform scalar load, 0 or 1
    vf4* dst = (vf4*)(pert + (size_t)r * HH);
#pragma unroll
    for (int k = 0; k < 4; ++k) {
      vf4 p = sv[k] * yf;
      __builtin_nontemporal_store(p, &dst[tid + 256 * k]);
    }
  }
}

extern "C" void kernel_launch(void* const* d_in, const int* in_sizes, int n_in,
                              void* d_out, int out_size, void* d_ws, size_t ws_size,
                              hipStream_t stream) {
  // setup_inputs order: x, y, W1, W2, bias1, bias2
  const int*   y     = (const int*)d_in[1];
  const float* W1    = (const float*)d_in[2];
  const float* W2    = (const float*)d_in[3];
  const float* bias2 = (const float*)d_in[5];
  float* out = (float*)d_out;

  float* nscaled = (float*)d_ws;  // HH floats

  prep_kernel<<<HH + OO, 256, 0, stream>>>(W1, W2, bias2, nscaled, out);
  write_kernel<<<OO * (BB / BCHUNK), 256, 0, stream>>>(y, W2, nscaled, out);
}